// Round 1
// baseline (1218.573 us; speedup 1.0000x reference)
//
#include <hip/hip_runtime.h>

#define T_LEN 1024
#define BATCH 64
#define NHID  1024
#define H2    2048
#define NVOC  50257
#define G4    8192
#define KCAT  3072
#define LS    56   // LDS row stride in bf16: 16B-aligned rows, 2-way-max bank aliasing

typedef __attribute__((ext_vector_type(4))) float  f4;
typedef __attribute__((ext_vector_type(4))) float  f32x4;
typedef __attribute__((ext_vector_type(8))) __bf16 bf8;
typedef __attribute__((ext_vector_type(4))) __bf16 bf4;

__device__ inline float fast_tanh(float x) {
    float e = __expf(2.0f * x);
    return 1.0f - 2.0f / (e + 1.0f);   // graceful at e=inf -> 1, e=0 -> -1
}
__device__ inline float fast_sig(float x) {
    return 1.0f / (1.0f + __expf(-x));
}

// ---------------------------------------------------------------------------
// attUa (k,n) fp32 -> attUaT (n,k) bf16, LDS-tiled transpose
// ---------------------------------------------------------------------------
__global__ __launch_bounds__(256) void transpose_ua(const float* __restrict__ ua,
                                                    __bf16* __restrict__ uaT) {
    __shared__ float tile[64][65];
    const int tid = threadIdx.x;
    const int kb = (blockIdx.x & 15) * 64, nb = (blockIdx.x >> 4) * 64;
#pragma unroll
    for (int i = 0; i < 16; ++i) {
        int idx = tid + 256 * i;
        int kr = idx >> 6, nc = idx & 63;
        tile[kr][nc] = ua[(size_t)(kb + kr) * NHID + nb + nc];
    }
    __syncthreads();
#pragma unroll
    for (int i = 0; i < 16; ++i) {
        int idx = tid + 256 * i;
        int nr = idx >> 6, kc = idx & 63;
        uaT[(size_t)(nb + nr) * NHID + kb + kc] = (__bf16)tile[kc][nr];
    }
}

// ---------------------------------------------------------------------------
// emb gather + h_prev -> A_gates bf16 [b][3072] (cols 0..1023 emb, 1024..2047 h)
// ---------------------------------------------------------------------------
__global__ void prep_emb_h(const int* __restrict__ inp, const float* __restrict__ enc,
                           const float* __restrict__ h, __bf16* __restrict__ Ag) {
    const int b = blockIdx.x, tid = threadIdx.x;
    const int tok = inp[b];
#pragma unroll
    for (int i = 0; i < 4; ++i) {
        int n = tid + 256 * i;
        Ag[(size_t)b * KCAT + n]        = (__bf16)enc[(size_t)tok * NHID + n];
        Ag[(size_t)b * KCAT + NHID + n] = (__bf16)h[(size_t)b * NHID + n];
    }
}

// ---------------------------------------------------------------------------
// Small MFMA GEMM: M=64, N-tile=64. A bf16 [64][lda] (k-contig).
// B fp32 row-major [k][ldb] in two segments (k<k1 -> B1, else B2), transposed in LDS.
// mode 0: out[m*ldo+n] fp32    mode 1: out[n*64+m] fp32 (transposed, float4)
// Used for: hWa = h_prev @ attWa (mode 1) and gates (mode 0).
// ---------------------------------------------------------------------------
__global__ __launch_bounds__(256) void small_gemm(
    const __bf16* __restrict__ A, int lda, int K, int k1,
    const float* __restrict__ B1, const float* __restrict__ B2, int ldb,
    float* __restrict__ out, int ldo, int mode) {
    __shared__ __bf16 As[64 * LS];
    __shared__ __bf16 Bs[64 * LS];
    const int tid = threadIdx.x;
    const int lane = tid & 63, wave = tid >> 6;
    const int quad = lane >> 4, l15 = lane & 15;
    const int n0 = blockIdx.x * 64;
    const int ar = tid >> 2, ac = (tid & 3) * 8;

    f32x4 acc[4] = {};

    for (int k0 = 0; k0 < K; k0 += 32) {
        __syncthreads();
        *(bf8*)&As[ar * LS + ac] = *(const bf8*)(A + (size_t)ar * lda + k0 + ac);
#pragma unroll
        for (int j = 0; j < 2; ++j) {
            int idx = tid + 256 * j;
            int kr = idx >> 4, nc = (idx & 15) * 4;
            int kg = k0 + kr;
            const float* src = (kg < k1) ? (B1 + (size_t)kg * ldb)
                                         : (B2 + (size_t)(kg - k1) * ldb);
            f4 v = *(const f4*)(src + n0 + nc);
#pragma unroll
            for (int i = 0; i < 4; ++i) Bs[(nc + i) * LS + kr] = (__bf16)v[i];
        }
        __syncthreads();
        bf8 bfr = *(const bf8*)&Bs[(wave * 16 + l15) * LS + quad * 8];
#pragma unroll
        for (int mi = 0; mi < 4; ++mi) {
            bf8 af = *(const bf8*)&As[(mi * 16 + l15) * LS + quad * 8];
            acc[mi] = __builtin_amdgcn_mfma_f32_16x16x32_bf16(af, bfr, acc[mi], 0, 0, 0);
        }
    }
    const int n = n0 + wave * 16 + l15;
    if (mode == 0) {
#pragma unroll
        for (int mi = 0; mi < 4; ++mi)
#pragma unroll
            for (int r = 0; r < 4; ++r)
                out[(size_t)(mi * 16 + quad * 4 + r) * ldo + n] = acc[mi][r];
    } else {
#pragma unroll
        for (int mi = 0; mi < 4; ++mi)
            *(f4*)&out[(size_t)n * 64 + mi * 16 + quad * 4] = acc[mi];
    }
}

// ---------------------------------------------------------------------------
// THE BIG ONE: score = tanh(mem_pool @ attUa + hWa) @ attV, fused epilogue.
// C-tile 128x128, 4 waves (2x2), bf16 MFMA 16x16x32, K=1024.
// A: mem_pool fp32 rows (cvt on stage). B: attUaT bf16 [n][k] (direct copy).
// Epilogue: tanh(+hWaT[n][b])*attV[n], 16-lane row reduce, atomicAdd scoreT[b][t].
// Row r = t*64+b  ->  b = local row (0..63 pattern), t = mb*2 + wM (wave-uniform).
// ---------------------------------------------------------------------------
__global__ __launch_bounds__(256) void score_gemm(
    const float* __restrict__ mem, const __bf16* __restrict__ uaT,
    const float* __restrict__ hWaT, const float* __restrict__ attV,
    float* __restrict__ scoreT) {
    __shared__ __bf16 As[128 * LS];
    __shared__ __bf16 Bs[128 * LS];
    const int tid = threadIdx.x;
    const int lane = tid & 63, wave = tid >> 6;
    const int wM = wave >> 1, wN = wave & 1;
    const int quad = lane >> 4, l15 = lane & 15;
    const int mb = blockIdx.x >> 3, nb = blockIdx.x & 7;  // N fast -> A-tile L2 reuse
    const int n0 = nb * 128;

    const int arow = tid >> 1, ahalf = (tid & 1) * 16;
    const float*  aptr = mem + (size_t)(mb * 128 + arow) * NHID + ahalf;
    const __bf16* bptr = uaT + (size_t)(n0 + arow) * NHID + ahalf;

    f4  ga[4];
    bf8 gb[2];
#pragma unroll
    for (int j = 0; j < 4; ++j) ga[j] = *(const f4*)(aptr + 4 * j);
#pragma unroll
    for (int j = 0; j < 2; ++j) gb[j] = *(const bf8*)(bptr + 8 * j);

    f32x4 acc[4][4] = {};

    for (int k0 = 0; k0 < NHID; k0 += 32) {
        __syncthreads();
#pragma unroll
        for (int j = 0; j < 4; ++j) {
            bf4 w;
            w[0] = (__bf16)ga[j][0]; w[1] = (__bf16)ga[j][1];
            w[2] = (__bf16)ga[j][2]; w[3] = (__bf16)ga[j][3];
            *(bf4*)&As[arow * LS + ahalf + 4 * j] = w;
        }
#pragma unroll
        for (int j = 0; j < 2; ++j) *(bf8*)&Bs[arow * LS + ahalf + 8 * j] = gb[j];
        __syncthreads();
        if (k0 + 32 < NHID) {   // prefetch next tile into VGPRs, overlaps MFMA
#pragma unroll
            for (int j = 0; j < 4; ++j) ga[j] = *(const f4*)(aptr + k0 + 32 + 4 * j);
#pragma unroll
            for (int j = 0; j < 2; ++j) gb[j] = *(const bf8*)(bptr + k0 + 32 + 8 * j);
        }
        bf8 af[4], bfr[4];
#pragma unroll
        for (int i = 0; i < 4; ++i)
            af[i] = *(const bf8*)&As[(wM * 64 + i * 16 + l15) * LS + quad * 8];
#pragma unroll
        for (int i = 0; i < 4; ++i)
            bfr[i] = *(const bf8*)&Bs[(wN * 64 + i * 16 + l15) * LS + quad * 8];
#pragma unroll
        for (int mi = 0; mi < 4; ++mi)
#pragma unroll
            for (int ni = 0; ni < 4; ++ni)
                acc[mi][ni] = __builtin_amdgcn_mfma_f32_16x16x32_bf16(
                    af[mi], bfr[ni], acc[mi][ni], 0, 0, 0);
    }

    // fused epilogue: score partial = sum_n tanh(acc + hWa[b][n]) * attV[n]
    const int tglob = mb * 2 + wM;
#pragma unroll
    for (int mi = 0; mi < 4; ++mi) {
        float rs[4] = {0.f, 0.f, 0.f, 0.f};
#pragma unroll
        for (int ni = 0; ni < 4; ++ni) {
            int n = n0 + wN * 64 + ni * 16 + l15;
            f4 hw = *(const f4*)&hWaT[(size_t)n * 64 + mi * 16 + quad * 4];
            float av = attV[n];
#pragma unroll
            for (int r = 0; r < 4; ++r)
                rs[r] += fast_tanh(acc[mi][ni][r] + hw[r]) * av;
        }
#pragma unroll
        for (int r = 0; r < 4; ++r) {
            float v = rs[r];
            v += __shfl_xor(v, 1); v += __shfl_xor(v, 2);
            v += __shfl_xor(v, 4); v += __shfl_xor(v, 8);
            if (l15 == 0) {
                int b = mi * 16 + quad * 4 + r;
                atomicAdd(&scoreT[b * T_LEN + tglob], v);
            }
        }
    }
}

// ---------------------------------------------------------------------------
// softmax over t for each b (scoreT layout [b][t])
// ---------------------------------------------------------------------------
__global__ void softmax_k(const float* __restrict__ scoreT, float* __restrict__ wts) {
    const int b = blockIdx.x, tid = threadIdx.x;
    const int lane = tid & 63, wave = tid >> 6;
    __shared__ float red[4];
    __shared__ float red2[4];
    float s[4];
    float mx = -1e30f;
#pragma unroll
    for (int i = 0; i < 4; ++i) {
        s[i] = scoreT[b * T_LEN + tid + 256 * i];
        mx = fmaxf(mx, s[i]);
    }
#pragma unroll
    for (int o = 1; o < 64; o <<= 1) mx = fmaxf(mx, __shfl_xor(mx, o));
    if (lane == 0) red[wave] = mx;
    __syncthreads();
    mx = fmaxf(fmaxf(red[0], red[1]), fmaxf(red[2], red[3]));
    float e[4], sum = 0.f;
#pragma unroll
    for (int i = 0; i < 4; ++i) { e[i] = __expf(s[i] - mx); sum += e[i]; }
#pragma unroll
    for (int o = 1; o < 64; o <<= 1) sum += __shfl_xor(sum, o);
    if (lane == 0) red2[wave] = sum;
    __syncthreads();
    sum = red2[0] + red2[1] + red2[2] + red2[3];
    float inv = 1.0f / sum;
#pragma unroll
    for (int i = 0; i < 4; ++i) wts[b * T_LEN + tid + 256 * i] = e[i] * inv;
}

// ---------------------------------------------------------------------------
// contextVec[b][n] = sum_t wts[b][t] * mem[t][b][n]; t-split with atomics
// ---------------------------------------------------------------------------
__global__ void context_k(const float* __restrict__ wts, const float* __restrict__ mem,
                          float* __restrict__ ctx) {
    const int b = blockIdx.x >> 3, tc = blockIdx.x & 7;
    const int n4 = threadIdx.x * 4;
    f4 acc = {0.f, 0.f, 0.f, 0.f};
    const int t0 = tc * 128;
    for (int t = t0; t < t0 + 128; ++t) {
        float w = wts[b * T_LEN + t];
        f4 m = *(const f4*)(mem + ((size_t)t * BATCH + b) * NHID + n4);
        acc += w * m;
    }
#pragma unroll
    for (int i = 0; i < 4; ++i) atomicAdd(&ctx[(size_t)b * NHID + n4 + i], acc[i]);
}

__global__ void ctx_cvt(const float* __restrict__ ctx, __bf16* __restrict__ Ag) {
    const int b = blockIdx.x, tid = threadIdx.x;
#pragma unroll
    for (int i = 0; i < 4; ++i) {
        int n = tid + 256 * i;
        Ag[(size_t)b * KCAT + H2 + n] = (__bf16)ctx[(size_t)b * NHID + n];
    }
}

// ---------------------------------------------------------------------------
// LSTM cell elementwise; writes ct, ht outputs + bf16 ht for decoder
// ---------------------------------------------------------------------------
__global__ void lstm_k(const float* __restrict__ gates, const float* __restrict__ bl,
                       const float* __restrict__ cprev, float* __restrict__ out_ct,
                       float* __restrict__ out_ht, __bf16* __restrict__ htb) {
    const int idx = blockIdx.x * 256 + threadIdx.x;  // 64*2048
    const int b = idx >> 11, k = idx & 2047;
    float gi = gates[(size_t)b * G4 + k]          + bl[k];
    float gf = gates[(size_t)b * G4 + H2 + k]     + bl[H2 + k];
    float gg = gates[(size_t)b * G4 + 2 * H2 + k] + bl[2 * H2 + k];
    float go = gates[(size_t)b * G4 + 3 * H2 + k] + bl[3 * H2 + k];
    float ct = fast_sig(gf) * cprev[idx] + fast_sig(gi) * fast_tanh(gg);
    float ht = fast_sig(go) * fast_tanh(ct);
    out_ct[idx] = ct;
    if (k < NHID) {
        out_ht[(size_t)b * NHID + k] = ht;
        htb[(size_t)b * NHID + k]    = (__bf16)ht;
    }
}

// ---------------------------------------------------------------------------
// decoded = ht @ dec_w.T + dec_b. M=64, N=50257 (tail-masked), K=1024.
// dec_w is already [v][k] (B-transposed layout): direct staging w/ fp32->bf16.
// ---------------------------------------------------------------------------
__global__ __launch_bounds__(256) void dec_gemm(
    const __bf16* __restrict__ htb, const float* __restrict__ dw,
    const float* __restrict__ db, float* __restrict__ outd) {
    __shared__ __bf16 As[64 * LS];
    __shared__ __bf16 Bs[128 * LS];
    const int tid = threadIdx.x;
    const int lane = tid & 63, wave = tid >> 6;
    const int quad = lane >> 4, l15 = lane & 15;
    const int n0 = blockIdx.x * 128;
    const int ar = tid >> 2, ac = (tid & 3) * 8;
    const int br = tid >> 1, bc = (tid & 1) * 16;
    const int vrow = n0 + br;

    f32x4 acc[4][2] = {};

    for (int k0 = 0; k0 < NHID; k0 += 32) {
        __syncthreads();
        *(bf8*)&As[ar * LS + ac] = *(const bf8*)(htb + (size_t)ar * NHID + k0 + ac);
#pragma unroll
        for (int j = 0; j < 4; ++j) {
            f4 v = {0.f, 0.f, 0.f, 0.f};
            if (vrow < NVOC) v = *(const f4*)(dw + (size_t)vrow * NHID + k0 + bc + 4 * j);
            bf4 w;
            w[0] = (__bf16)v[0]; w[1] = (__bf16)v[1];
            w[2] = (__bf16)v[2]; w[3] = (__bf16)v[3];
            *(bf4*)&Bs[br * LS + bc + 4 * j] = w;
        }
        __syncthreads();
#pragma unroll
        for (int ni = 0; ni < 2; ++ni) {
            bf8 bfr = *(const bf8*)&Bs[(wave * 32 + ni * 16 + l15) * LS + quad * 8];
#pragma unroll
            for (int mi = 0; mi < 4; ++mi) {
                bf8 af = *(const bf8*)&As[(mi * 16 + l15) * LS + quad * 8];
                acc[mi][ni] = __builtin_amdgcn_mfma_f32_16x16x32_bf16(af, bfr, acc[mi][ni], 0, 0, 0);
            }
        }
    }
#pragma unroll
    for (int ni = 0; ni < 2; ++ni) {
        int n = n0 + wave * 32 + ni * 16 + l15;
        if (n < NVOC) {
            float bb = db[n];
#pragma unroll
            for (int mi = 0; mi < 4; ++mi)
#pragma unroll
                for (int r = 0; r < 4; ++r)
                    outd[(size_t)(mi * 16 + quad * 4 + r) * NVOC + n] = acc[mi][ni][r] + bb;
        }
    }
}

// ---------------------------------------------------------------------------
extern "C" void kernel_launch(void* const* d_in, const int* in_sizes, int n_in,
                              void* d_out, int out_size, void* d_ws, size_t ws_size,
                              hipStream_t stream) {
    (void)in_sizes; (void)n_in; (void)out_size; (void)ws_size;
    const int*   inp   = (const int*)d_in[0];
    const float* mem   = (const float*)d_in[1];
    const float* hprev = (const float*)d_in[2];
    const float* cprev = (const float*)d_in[3];
    const float* encw  = (const float*)d_in[4];
    const float* attWa = (const float*)d_in[5];
    const float* attUa = (const float*)d_in[6];
    const float* attV  = (const float*)d_in[7];
    const float* Wih   = (const float*)d_in[8];
    const float* Whh   = (const float*)d_in[9];
    const float* blstm = (const float*)d_in[10];
    const float* decw  = (const float*)d_in[11];
    const float* decb  = (const float*)d_in[12];

    char* ws = (char*)d_ws;
    float*  scoreT = (float*)(ws);              // 256 KB  [b][t]
    float*  wts    = (float*)(ws + 262144);     // 256 KB  [b][t]
    float*  hWaT   = (float*)(ws + 524288);     // 256 KB  [n][b]
    float*  ctx    = (float*)(ws + 786432);     // 256 KB  [b][n]
    float*  gates  = (float*)(ws + 1048576);    // 2 MB    [b][8192]
    __bf16* Ag     = (__bf16*)(ws + 3145728);   // 384 KB  [b][3072] = emb|h|ctx
    __bf16* htb    = (__bf16*)(ws + 3538944);   // 128 KB  [b][1024]
    __bf16* uaT    = (__bf16*)(ws + 3670016);   // 2 MB    [n][k]

    float* outdec = (float*)d_out;                       // 64 x 50257
    float* outht  = outdec + (size_t)BATCH * NVOC;       // 64 x 1024
    float* outct  = outht + BATCH * NHID;                // 64 x 2048

    hipMemsetAsync(scoreT, 0, 262144, stream);
    hipMemsetAsync(ctx, 0, 262144, stream);
    hipLaunchKernelGGL(transpose_ua, dim3(256), dim3(256), 0, stream, attUa, uaT);
    hipLaunchKernelGGL(prep_emb_h, dim3(64), dim3(256), 0, stream, inp, encw, hprev, Ag);
    // hWa = h_prev @ attWa  (A = h slice of Ag), out transposed [n][b]
    hipLaunchKernelGGL(small_gemm, dim3(16), dim3(256), 0, stream,
                       Ag + NHID, KCAT, NHID, NHID, attWa, attWa, NHID, hWaT, 64, 1);
    hipLaunchKernelGGL(score_gemm, dim3(4096), dim3(256), 0, stream,
                       mem, uaT, hWaT, attV, scoreT);
    hipLaunchKernelGGL(softmax_k, dim3(64), dim3(256), 0, stream, scoreT, wts);
    hipLaunchKernelGGL(context_k, dim3(512), dim3(256), 0, stream, wts, mem, ctx);
    hipLaunchKernelGGL(ctx_cvt, dim3(64), dim3(256), 0, stream, ctx, Ag);
    // gates = emb @ W_ih + [h|ctx] @ W_hh  (bias added in lstm_k)
    hipLaunchKernelGGL(small_gemm, dim3(128), dim3(256), 0, stream,
                       Ag, KCAT, KCAT, NHID, Wih, Whh, G4, gates, G4, 0);
    hipLaunchKernelGGL(lstm_k, dim3(512), dim3(256), 0, stream,
                       gates, blstm, cprev, outct, outht, htb);
    hipLaunchKernelGGL(dec_gemm, dim3((NVOC + 127) / 128), dim3(256), 0, stream,
                       htb, decw, decb, outdec);
}

// Round 2
// 1175.730 us; speedup vs baseline: 1.0364x; 1.0364x over previous
//
#include <hip/hip_runtime.h>

#define T_LEN 1024
#define BATCH 64
#define NHID  1024
#define H2    2048
#define NVOC  50257
#define G4    8192
#define KCAT  3072
#define LS    56   // LDS row stride (bf16) for the transpose-staging GEMMs

typedef __attribute__((ext_vector_type(4))) float  f4;
typedef __attribute__((ext_vector_type(4))) float  f32x4;
typedef __attribute__((ext_vector_type(8))) __bf16 bf8;
typedef __attribute__((ext_vector_type(4))) __bf16 bf4;

#define GPTR(p) ((const __attribute__((address_space(1))) void*)(p))
#define LPTR(p) ((__attribute__((address_space(3))) void*)(p))

__device__ inline float fast_tanh(float x) {
    float e = __expf(2.0f * x);
    return 1.0f - 2.0f / (e + 1.0f);
}
__device__ inline float fast_sig(float x) {
    return 1.0f / (1.0f + __expf(-x));
}

// ---------------------------------------------------------------------------
// mem_pool fp32 -> bf16, straight copy (enables global_load_lds + L3 residency)
// ---------------------------------------------------------------------------
__global__ __launch_bounds__(256) void cvt_mem(const float* __restrict__ mem,
                                               __bf16* __restrict__ memb) {
    const size_t i = ((size_t)blockIdx.x * 256 + threadIdx.x) * 8;
    f4 a = *(const f4*)(mem + i);
    f4 b = *(const f4*)(mem + i + 4);
    bf8 w;
    w[0] = (__bf16)a[0]; w[1] = (__bf16)a[1]; w[2] = (__bf16)a[2]; w[3] = (__bf16)a[3];
    w[4] = (__bf16)b[0]; w[5] = (__bf16)b[1]; w[6] = (__bf16)b[2]; w[7] = (__bf16)b[3];
    *(bf8*)(memb + i) = w;
}

// ---------------------------------------------------------------------------
// attUa (k,n) fp32 -> attUaT (n,k) bf16, LDS-tiled transpose
// ---------------------------------------------------------------------------
__global__ __launch_bounds__(256) void transpose_ua(const float* __restrict__ ua,
                                                    __bf16* __restrict__ uaT) {
    __shared__ float tile[64][65];
    const int tid = threadIdx.x;
    const int kb = (blockIdx.x & 15) * 64, nb = (blockIdx.x >> 4) * 64;
#pragma unroll
    for (int i = 0; i < 16; ++i) {
        int idx = tid + 256 * i;
        int kr = idx >> 6, nc = idx & 63;
        tile[kr][nc] = ua[(size_t)(kb + kr) * NHID + nb + nc];
    }
    __syncthreads();
#pragma unroll
    for (int i = 0; i < 16; ++i) {
        int idx = tid + 256 * i;
        int nr = idx >> 6, kc = idx & 63;
        uaT[(size_t)(nb + nr) * NHID + kb + kc] = (__bf16)tile[kc][nr];
    }
}

// ---------------------------------------------------------------------------
// emb gather + h_prev -> A_gates bf16 [b][3072]
// ---------------------------------------------------------------------------
__global__ void prep_emb_h(const int* __restrict__ inp, const float* __restrict__ enc,
                           const float* __restrict__ h, __bf16* __restrict__ Ag) {
    const int b = blockIdx.x, tid = threadIdx.x;
    const int tok = inp[b];
#pragma unroll
    for (int i = 0; i < 4; ++i) {
        int n = tid + 256 * i;
        Ag[(size_t)b * KCAT + n]        = (__bf16)enc[(size_t)tok * NHID + n];
        Ag[(size_t)b * KCAT + NHID + n] = (__bf16)h[(size_t)b * NHID + n];
    }
}

// ---------------------------------------------------------------------------
// Small MFMA GEMM (M=64, N-tile=64), B fp32 transposed in LDS on the fly.
// ---------------------------------------------------------------------------
__global__ __launch_bounds__(256) void small_gemm(
    const __bf16* __restrict__ A, int lda, int K, int k1,
    const float* __restrict__ B1, const float* __restrict__ B2, int ldb,
    float* __restrict__ out, int ldo, int mode) {
    __shared__ __bf16 As[64 * LS];
    __shared__ __bf16 Bs[64 * LS];
    const int tid = threadIdx.x;
    const int lane = tid & 63, wave = tid >> 6;
    const int quad = lane >> 4, l15 = lane & 15;
    const int n0 = blockIdx.x * 64;
    const int ar = tid >> 2, ac = (tid & 3) * 8;

    f32x4 acc[4] = {};

    for (int k0 = 0; k0 < K; k0 += 32) {
        __syncthreads();
        *(bf8*)&As[ar * LS + ac] = *(const bf8*)(A + (size_t)ar * lda + k0 + ac);
#pragma unroll
        for (int j = 0; j < 2; ++j) {
            int idx = tid + 256 * j;
            int kr = idx >> 4, nc = (idx & 15) * 4;
            int kg = k0 + kr;
            const float* src = (kg < k1) ? (B1 + (size_t)kg * ldb)
                                         : (B2 + (size_t)(kg - k1) * ldb);
            f4 v = *(const f4*)(src + n0 + nc);
#pragma unroll
            for (int i = 0; i < 4; ++i) Bs[(nc + i) * LS + kr] = (__bf16)v[i];
        }
        __syncthreads();
        bf8 bfr = *(const bf8*)&Bs[(wave * 16 + l15) * LS + quad * 8];
#pragma unroll
        for (int mi = 0; mi < 4; ++mi) {
            bf8 af = *(const bf8*)&As[(mi * 16 + l15) * LS + quad * 8];
            acc[mi] = __builtin_amdgcn_mfma_f32_16x16x32_bf16(af, bfr, acc[mi], 0, 0, 0);
        }
    }
    const int n = n0 + wave * 16 + l15;
    if (mode == 0) {
#pragma unroll
        for (int mi = 0; mi < 4; ++mi)
#pragma unroll
            for (int r = 0; r < 4; ++r)
                out[(size_t)(mi * 16 + quad * 4 + r) * ldo + n] = acc[mi][r];
    } else {
#pragma unroll
        for (int mi = 0; mi < 4; ++mi)
            *(f4*)&out[(size_t)n * 64 + mi * 16 + quad * 4] = acc[mi];
    }
}

// ---------------------------------------------------------------------------
// score_gemm v2: bf16 A (pre-converted), m97-style global_load_lds staging.
// C-tile 128x128, 4 waves (2x2). XCD-aware swizzle: the 8 nb-blocks sharing
// an mb land on one XCD (block->XCD ~ blk%8) so the A-tile is fetched into
// that XCD's L2 once. LDS layout contiguous [row][32k] (global_load_lds
// requires wave-uniform base + lane*16; no padding allowed).
// ---------------------------------------------------------------------------
__global__ __launch_bounds__(256) void score_gemm(
    const __bf16* __restrict__ memb, const __bf16* __restrict__ uaT,
    const float* __restrict__ hWaT, const float* __restrict__ attV,
    float* __restrict__ scoreT) {
    __shared__ __bf16 As[128 * 32];
    __shared__ __bf16 Bs[128 * 32];
    const int tid = threadIdx.x;
    const int lane = tid & 63, wave = tid >> 6;
    const int wM = wave >> 1, wN = wave & 1;
    const int quad = lane >> 4, l15 = lane & 15;
    const int bidx = blockIdx.x;
    const int mb = (bidx >> 6) * 8 + (bidx & 7);   // same-XCD group shares mb
    const int nb = (bidx >> 3) & 7;
    const int n0 = nb * 128, m0 = mb * 128;

    // staging geometry: chunk c (0..7) = rows [c*16, c*16+16); lane l covers
    // row c*16 + l/4, elem offset (l&3)*8 (16B). LDS dest = As + c*512 (+l*16B by HW)
    const int srow = lane >> 2, scol = (lane & 3) * 8;

    f32x4 acc[4][4] = {};

    for (int k0 = 0; k0 < NHID; k0 += 32) {
        __syncthreads();
#pragma unroll
        for (int j = 0; j < 2; ++j) {
            const int c = wave * 2 + j;
            __builtin_amdgcn_global_load_lds(
                GPTR(memb + (size_t)(m0 + c * 16 + srow) * NHID + k0 + scol),
                LPTR(As + c * 512), 16, 0, 0);
            __builtin_amdgcn_global_load_lds(
                GPTR(uaT + (size_t)(n0 + c * 16 + srow) * NHID + k0 + scol),
                LPTR(Bs + c * 512), 16, 0, 0);
        }
        __syncthreads();
        bf8 af[4], bfr[4];
#pragma unroll
        for (int i = 0; i < 4; ++i)
            af[i] = *(const bf8*)&As[(wM * 64 + i * 16 + l15) * 32 + quad * 8];
#pragma unroll
        for (int i = 0; i < 4; ++i)
            bfr[i] = *(const bf8*)&Bs[(wN * 64 + i * 16 + l15) * 32 + quad * 8];
#pragma unroll
        for (int mi = 0; mi < 4; ++mi)
#pragma unroll
            for (int ni = 0; ni < 4; ++ni)
                acc[mi][ni] = __builtin_amdgcn_mfma_f32_16x16x32_bf16(
                    af[mi], bfr[ni], acc[mi][ni], 0, 0, 0);
    }

    const int tglob = mb * 2 + wM;
#pragma unroll
    for (int mi = 0; mi < 4; ++mi) {
        float rs[4] = {0.f, 0.f, 0.f, 0.f};
#pragma unroll
        for (int ni = 0; ni < 4; ++ni) {
            int n = n0 + wN * 64 + ni * 16 + l15;
            f4 hw = *(const f4*)&hWaT[(size_t)n * 64 + mi * 16 + quad * 4];
            float av = attV[n];
#pragma unroll
            for (int r = 0; r < 4; ++r)
                rs[r] += fast_tanh(acc[mi][ni][r] + hw[r]) * av;
        }
#pragma unroll
        for (int r = 0; r < 4; ++r) {
            float v = rs[r];
            v += __shfl_xor(v, 1); v += __shfl_xor(v, 2);
            v += __shfl_xor(v, 4); v += __shfl_xor(v, 8);
            if (l15 == 0) {
                int b = mi * 16 + quad * 4 + r;
                atomicAdd(&scoreT[b * T_LEN + tglob], v);
            }
        }
    }
}

// ---------------------------------------------------------------------------
// fallback score_gemm reading fp32 mem directly (used if ws too small)
// ---------------------------------------------------------------------------
__global__ __launch_bounds__(256) void score_gemm_f32(
    const float* __restrict__ mem, const __bf16* __restrict__ uaT,
    const float* __restrict__ hWaT, const float* __restrict__ attV,
    float* __restrict__ scoreT) {
    __shared__ __bf16 As[128 * LS];
    __shared__ __bf16 Bs[128 * LS];
    const int tid = threadIdx.x;
    const int lane = tid & 63, wave = tid >> 6;
    const int wM = wave >> 1, wN = wave & 1;
    const int quad = lane >> 4, l15 = lane & 15;
    const int mb = blockIdx.x >> 3, nb = blockIdx.x & 7;
    const int n0 = nb * 128;
    const int arow = tid >> 1, ahalf = (tid & 1) * 16;
    const float*  aptr = mem + (size_t)(mb * 128 + arow) * NHID + ahalf;
    const __bf16* bptr = uaT + (size_t)(n0 + arow) * NHID + ahalf;
    f4  ga[4];
    bf8 gb[2];
#pragma unroll
    for (int j = 0; j < 4; ++j) ga[j] = *(const f4*)(aptr + 4 * j);
#pragma unroll
    for (int j = 0; j < 2; ++j) gb[j] = *(const bf8*)(bptr + 8 * j);
    f32x4 acc[4][4] = {};
    for (int k0 = 0; k0 < NHID; k0 += 32) {
        __syncthreads();
#pragma unroll
        for (int j = 0; j < 4; ++j) {
            bf4 w;
            w[0] = (__bf16)ga[j][0]; w[1] = (__bf16)ga[j][1];
            w[2] = (__bf16)ga[j][2]; w[3] = (__bf16)ga[j][3];
            *(bf4*)&As[arow * LS + ahalf + 4 * j] = w;
        }
#pragma unroll
        for (int j = 0; j < 2; ++j) *(bf8*)&Bs[arow * LS + ahalf + 8 * j] = gb[j];
        __syncthreads();
        if (k0 + 32 < NHID) {
#pragma unroll
            for (int j = 0; j < 4; ++j) ga[j] = *(const f4*)(aptr + k0 + 32 + 4 * j);
#pragma unroll
            for (int j = 0; j < 2; ++j) gb[j] = *(const bf8*)(bptr + k0 + 32 + 8 * j);
        }
        bf8 af[4], bfr[4];
#pragma unroll
        for (int i = 0; i < 4; ++i)
            af[i] = *(const bf8*)&As[(wM * 64 + i * 16 + l15) * LS + quad * 8];
#pragma unroll
        for (int i = 0; i < 4; ++i)
            bfr[i] = *(const bf8*)&Bs[(wN * 64 + i * 16 + l15) * LS + quad * 8];
#pragma unroll
        for (int mi = 0; mi < 4; ++mi)
#pragma unroll
            for (int ni = 0; ni < 4; ++ni)
                acc[mi][ni] = __builtin_amdgcn_mfma_f32_16x16x32_bf16(
                    af[mi], bfr[ni], acc[mi][ni], 0, 0, 0);
    }
    const int tglob = mb * 2 + wM;
#pragma unroll
    for (int mi = 0; mi < 4; ++mi) {
        float rs[4] = {0.f, 0.f, 0.f, 0.f};
#pragma unroll
        for (int ni = 0; ni < 4; ++ni) {
            int n = n0 + wN * 64 + ni * 16 + l15;
            f4 hw = *(const f4*)&hWaT[(size_t)n * 64 + mi * 16 + quad * 4];
            float av = attV[n];
#pragma unroll
            for (int r = 0; r < 4; ++r)
                rs[r] += fast_tanh(acc[mi][ni][r] + hw[r]) * av;
        }
#pragma unroll
        for (int r = 0; r < 4; ++r) {
            float v = rs[r];
            v += __shfl_xor(v, 1); v += __shfl_xor(v, 2);
            v += __shfl_xor(v, 4); v += __shfl_xor(v, 8);
            if (l15 == 0) {
                int b = mi * 16 + quad * 4 + r;
                atomicAdd(&scoreT[b * T_LEN + tglob], v);
            }
        }
    }
}

// ---------------------------------------------------------------------------
__global__ void softmax_k(const float* __restrict__ scoreT, float* __restrict__ wts) {
    const int b = blockIdx.x, tid = threadIdx.x;
    const int lane = tid & 63, wave = tid >> 6;
    __shared__ float red[4];
    __shared__ float red2[4];
    float s[4];
    float mx = -1e30f;
#pragma unroll
    for (int i = 0; i < 4; ++i) {
        s[i] = scoreT[b * T_LEN + tid + 256 * i];
        mx = fmaxf(mx, s[i]);
    }
#pragma unroll
    for (int o = 1; o < 64; o <<= 1) mx = fmaxf(mx, __shfl_xor(mx, o));
    if (lane == 0) red[wave] = mx;
    __syncthreads();
    mx = fmaxf(fmaxf(red[0], red[1]), fmaxf(red[2], red[3]));
    float e[4], sum = 0.f;
#pragma unroll
    for (int i = 0; i < 4; ++i) { e[i] = __expf(s[i] - mx); sum += e[i]; }
#pragma unroll
    for (int o = 1; o < 64; o <<= 1) sum += __shfl_xor(sum, o);
    if (lane == 0) red2[wave] = sum;
    __syncthreads();
    sum = red2[0] + red2[1] + red2[2] + red2[3];
    float inv = 1.0f / sum;
#pragma unroll
    for (int i = 0; i < 4; ++i) wts[b * T_LEN + tid + 256 * i] = e[i] * inv;
}

// ---------------------------------------------------------------------------
__global__ void context_k(const float* __restrict__ wts, const float* __restrict__ mem,
                          float* __restrict__ ctx) {
    const int b = blockIdx.x >> 3, tc = blockIdx.x & 7;
    const int n4 = threadIdx.x * 4;
    f4 acc = {0.f, 0.f, 0.f, 0.f};
    const int t0 = tc * 128;
    for (int t = t0; t < t0 + 128; ++t) {
        float w = wts[b * T_LEN + t];
        f4 m = *(const f4*)(mem + ((size_t)t * BATCH + b) * NHID + n4);
        acc += w * m;
    }
#pragma unroll
    for (int i = 0; i < 4; ++i) atomicAdd(&ctx[(size_t)b * NHID + n4 + i], acc[i]);
}

__global__ void ctx_cvt(const float* __restrict__ ctx, __bf16* __restrict__ Ag) {
    const int b = blockIdx.x, tid = threadIdx.x;
#pragma unroll
    for (int i = 0; i < 4; ++i) {
        int n = tid + 256 * i;
        Ag[(size_t)b * KCAT + H2 + n] = (__bf16)ctx[(size_t)b * NHID + n];
    }
}

// ---------------------------------------------------------------------------
__global__ void lstm_k(const float* __restrict__ gates, const float* __restrict__ bl,
                       const float* __restrict__ cprev, float* __restrict__ out_ct,
                       float* __restrict__ out_ht, __bf16* __restrict__ htb) {
    const int idx = blockIdx.x * 256 + threadIdx.x;
    const int b = idx >> 11, k = idx & 2047;
    float gi = gates[(size_t)b * G4 + k]          + bl[k];
    float gf = gates[(size_t)b * G4 + H2 + k]     + bl[H2 + k];
    float gg = gates[(size_t)b * G4 + 2 * H2 + k] + bl[2 * H2 + k];
    float go = gates[(size_t)b * G4 + 3 * H2 + k] + bl[3 * H2 + k];
    float ct = fast_sig(gf) * cprev[idx] + fast_sig(gi) * fast_tanh(gg);
    float ht = fast_sig(go) * fast_tanh(ct);
    out_ct[idx] = ct;
    if (k < NHID) {
        out_ht[(size_t)b * NHID + k] = ht;
        htb[(size_t)b * NHID + k]    = (__bf16)ht;
    }
}

// ---------------------------------------------------------------------------
__global__ __launch_bounds__(256) void dec_gemm(
    const __bf16* __restrict__ htb, const float* __restrict__ dw,
    const float* __restrict__ db, float* __restrict__ outd) {
    __shared__ __bf16 As[64 * LS];
    __shared__ __bf16 Bs[128 * LS];
    const int tid = threadIdx.x;
    const int lane = tid & 63, wave = tid >> 6;
    const int quad = lane >> 4, l15 = lane & 15;
    const int n0 = blockIdx.x * 128;
    const int ar = tid >> 2, ac = (tid & 3) * 8;
    const int br = tid >> 1, bc = (tid & 1) * 16;
    const int vrow = n0 + br;

    f32x4 acc[4][2] = {};

    for (int k0 = 0; k0 < NHID; k0 += 32) {
        __syncthreads();
        *(bf8*)&As[ar * LS + ac] = *(const bf8*)(htb + (size_t)ar * NHID + k0 + ac);
#pragma unroll
        for (int j = 0; j < 4; ++j) {
            f4 v = {0.f, 0.f, 0.f, 0.f};
            if (vrow < NVOC) v = *(const f4*)(dw + (size_t)vrow * NHID + k0 + bc + 4 * j);
            bf4 w;
            w[0] = (__bf16)v[0]; w[1] = (__bf16)v[1];
            w[2] = (__bf16)v[2]; w[3] = (__bf16)v[3];
            *(bf4*)&Bs[br * LS + bc + 4 * j] = w;
        }
        __syncthreads();
#pragma unroll
        for (int ni = 0; ni < 2; ++ni) {
            bf8 bfr = *(const bf8*)&Bs[(wave * 32 + ni * 16 + l15) * LS + quad * 8];
#pragma unroll
            for (int mi = 0; mi < 4; ++mi) {
                bf8 af = *(const bf8*)&As[(mi * 16 + l15) * LS + quad * 8];
                acc[mi][ni] = __builtin_amdgcn_mfma_f32_16x16x32_bf16(af, bfr, acc[mi][ni], 0, 0, 0);
            }
        }
    }
#pragma unroll
    for (int ni = 0; ni < 2; ++ni) {
        int n = n0 + wave * 32 + ni * 16 + l15;
        if (n < NVOC) {
            float bb = db[n];
#pragma unroll
            for (int mi = 0; mi < 4; ++mi)
#pragma unroll
                for (int r = 0; r < 4; ++r)
                    outd[(size_t)(mi * 16 + quad * 4 + r) * NVOC + n] = acc[mi][ni][r] + bb;
        }
    }
}

// ---------------------------------------------------------------------------
extern "C" void kernel_launch(void* const* d_in, const int* in_sizes, int n_in,
                              void* d_out, int out_size, void* d_ws, size_t ws_size,
                              hipStream_t stream) {
    (void)in_sizes; (void)n_in; (void)out_size;
    const int*   inp   = (const int*)d_in[0];
    const float* mem   = (const float*)d_in[1];
    const float* hprev = (const float*)d_in[2];
    const float* cprev = (const float*)d_in[3];
    const float* encw  = (const float*)d_in[4];
    const float* attWa = (const float*)d_in[5];
    const float* attUa = (const float*)d_in[6];
    const float* attV  = (const float*)d_in[7];
    const float* Wih   = (const float*)d_in[8];
    const float* Whh   = (const float*)d_in[9];
    const float* blstm = (const float*)d_in[10];
    const float* decw  = (const float*)d_in[11];
    const float* decb  = (const float*)d_in[12];

    char* ws = (char*)d_ws;
    float*  scoreT = (float*)(ws);              // 256 KB  [b][t]
    float*  wts    = (float*)(ws + 262144);     // 256 KB  [b][t]
    float*  hWaT   = (float*)(ws + 524288);     // 256 KB  [n][b]
    float*  ctx    = (float*)(ws + 786432);     // 256 KB  [b][n]
    float*  gates  = (float*)(ws + 1048576);    // 2 MB    [b][8192]
    __bf16* Ag     = (__bf16*)(ws + 3145728);   // 384 KB  [b][3072]
    __bf16* htb    = (__bf16*)(ws + 3538944);   // 128 KB  [b][1024]
    __bf16* uaT    = (__bf16*)(ws + 3670016);   // 2 MB    [n][k]
    __bf16* memb   = (__bf16*)(ws + 5767168);   // 134.2 MB [t*64+b][k]
    const size_t ws_need = 5767168 + (size_t)T_LEN * BATCH * NHID * 2;

    float* outdec = (float*)d_out;
    float* outht  = outdec + (size_t)BATCH * NVOC;
    float* outct  = outht + BATCH * NHID;

    hipMemsetAsync(scoreT, 0, 262144, stream);
    hipMemsetAsync(ctx, 0, 262144, stream);
    hipLaunchKernelGGL(transpose_ua, dim3(256), dim3(256), 0, stream, attUa, uaT);
    hipLaunchKernelGGL(prep_emb_h, dim3(64), dim3(256), 0, stream, inp, encw, hprev, Ag);
    hipLaunchKernelGGL(small_gemm, dim3(16), dim3(256), 0, stream,
                       Ag + NHID, KCAT, NHID, NHID, attWa, attWa, NHID, hWaT, 64, 1);
    if (ws_size >= ws_need) {
        hipLaunchKernelGGL(cvt_mem, dim3(32768), dim3(256), 0, stream, mem, memb);
        hipLaunchKernelGGL(score_gemm, dim3(4096), dim3(256), 0, stream,
                           memb, uaT, hWaT, attV, scoreT);
    } else {
        hipLaunchKernelGGL(score_gemm_f32, dim3(4096), dim3(256), 0, stream,
                           mem, uaT, hWaT, attV, scoreT);
    }
    hipLaunchKernelGGL(softmax_k, dim3(64), dim3(256), 0, stream, scoreT, wts);
    hipLaunchKernelGGL(context_k, dim3(512), dim3(256), 0, stream, wts, mem, ctx);
    hipLaunchKernelGGL(ctx_cvt, dim3(64), dim3(256), 0, stream, ctx, Ag);
    hipLaunchKernelGGL(small_gemm, dim3(128), dim3(256), 0, stream,
                       Ag, KCAT, KCAT, NHID, Wih, Whh, G4, gates, G4, 0);
    hipLaunchKernelGGL(lstm_k, dim3(512), dim3(256), 0, stream,
                       gates, blstm, cprev, outct, outht, htb);
    hipLaunchKernelGGL(dec_gemm, dim3((NVOC + 127) / 128), dim3(256), 0, stream,
                       htb, decw, decb, outdec);
}

// Round 3
// 1047.305 us; speedup vs baseline: 1.1635x; 1.1226x over previous
//
#include <hip/hip_runtime.h>

#define T_LEN 1024
#define BATCH 64
#define NHID  1024
#define H2    2048
#define NVOC  50257
#define G4    8192
#define KCAT  3072
#define LS    56   // LDS row stride (bf16) for the transpose-staging GEMMs

typedef __attribute__((ext_vector_type(4))) float  f4;
typedef __attribute__((ext_vector_type(4))) float  f32x4;
typedef __attribute__((ext_vector_type(8))) __bf16 bf8;
typedef __attribute__((ext_vector_type(4))) __bf16 bf4;

#define GPTR(p) ((const __attribute__((address_space(1))) void*)(p))
#define LPTR(p) ((__attribute__((address_space(3))) void*)(p))

__device__ inline float fast_tanh(float x) {
    float e = __expf(2.0f * x);
    return 1.0f - 2.0f / (e + 1.0f);
}
__device__ inline float fast_sig(float x) {
    return 1.0f / (1.0f + __expf(-x));
}

// ---------------------------------------------------------------------------
// mem_pool fp32 -> bf16
// ---------------------------------------------------------------------------
__global__ __launch_bounds__(256) void cvt_mem(const float* __restrict__ mem,
                                               __bf16* __restrict__ memb) {
    const size_t i = ((size_t)blockIdx.x * 256 + threadIdx.x) * 8;
    f4 a = *(const f4*)(mem + i);
    f4 b = *(const f4*)(mem + i + 4);
    bf8 w;
    w[0] = (__bf16)a[0]; w[1] = (__bf16)a[1]; w[2] = (__bf16)a[2]; w[3] = (__bf16)a[3];
    w[4] = (__bf16)b[0]; w[5] = (__bf16)b[1]; w[6] = (__bf16)b[2]; w[7] = (__bf16)b[3];
    *(bf8*)(memb + i) = w;
}

// ---------------------------------------------------------------------------
// attUa (k,n) fp32 -> attUaT (n,k) bf16
// ---------------------------------------------------------------------------
__global__ __launch_bounds__(256) void transpose_ua(const float* __restrict__ ua,
                                                    __bf16* __restrict__ uaT) {
    __shared__ float tile[64][65];
    const int tid = threadIdx.x;
    const int kb = (blockIdx.x & 15) * 64, nb = (blockIdx.x >> 4) * 64;
#pragma unroll
    for (int i = 0; i < 16; ++i) {
        int idx = tid + 256 * i;
        int kr = idx >> 6, nc = idx & 63;
        tile[kr][nc] = ua[(size_t)(kb + kr) * NHID + nb + nc];
    }
    __syncthreads();
#pragma unroll
    for (int i = 0; i < 16; ++i) {
        int idx = tid + 256 * i;
        int nr = idx >> 6, kc = idx & 63;
        uaT[(size_t)(nb + nr) * NHID + kb + kc] = (__bf16)tile[kc][nr];
    }
}

// ---------------------------------------------------------------------------
__global__ void prep_emb_h(const int* __restrict__ inp, const float* __restrict__ enc,
                           const float* __restrict__ h, __bf16* __restrict__ Ag) {
    const int b = blockIdx.x, tid = threadIdx.x;
    const int tok = inp[b];
#pragma unroll
    for (int i = 0; i < 4; ++i) {
        int n = tid + 256 * i;
        Ag[(size_t)b * KCAT + n]        = (__bf16)enc[(size_t)tok * NHID + n];
        Ag[(size_t)b * KCAT + NHID + n] = (__bf16)h[(size_t)b * NHID + n];
    }
}

// ---------------------------------------------------------------------------
// Small MFMA GEMM (M=64, N-tile=64), register-prefetch pipelined.
// ---------------------------------------------------------------------------
__global__ __launch_bounds__(256) void small_gemm(
    const __bf16* __restrict__ A, int lda, int K, int k1,
    const float* __restrict__ B1, const float* __restrict__ B2, int ldb,
    float* __restrict__ out, int ldo, int mode) {
    __shared__ __bf16 As[64 * LS];
    __shared__ __bf16 Bs[64 * LS];
    const int tid = threadIdx.x;
    const int lane = tid & 63, wave = tid >> 6;
    const int quad = lane >> 4, l15 = lane & 15;
    const int n0 = blockIdx.x * 64;
    const int ar = tid >> 2, ac = (tid & 3) * 8;
    const int kr = tid >> 4, nc = (tid & 15) * 4;

    f32x4 acc[4] = {};
    bf8 pa = *(const bf8*)(A + (size_t)ar * lda + ac);
    f4 pv[2];
#pragma unroll
    for (int j = 0; j < 2; ++j) {
        int kg = kr + 16 * j;
        const float* src = (kg < k1) ? (B1 + (size_t)kg * ldb)
                                     : (B2 + (size_t)(kg - k1) * ldb);
        pv[j] = *(const f4*)(src + n0 + nc);
    }

    for (int k0 = 0; k0 < K; k0 += 32) {
        __syncthreads();
        *(bf8*)&As[ar * LS + ac] = pa;
#pragma unroll
        for (int j = 0; j < 2; ++j)
#pragma unroll
            for (int i = 0; i < 4; ++i)
                Bs[(nc + i) * LS + kr + 16 * j] = (__bf16)pv[j][i];
        __syncthreads();
        if (k0 + 32 < K) {
            pa = *(const bf8*)(A + (size_t)ar * lda + k0 + 32 + ac);
#pragma unroll
            for (int j = 0; j < 2; ++j) {
                int kg = k0 + 32 + kr + 16 * j;
                const float* src = (kg < k1) ? (B1 + (size_t)kg * ldb)
                                             : (B2 + (size_t)(kg - k1) * ldb);
                pv[j] = *(const f4*)(src + n0 + nc);
            }
        }
        bf8 bfr = *(const bf8*)&Bs[(wave * 16 + l15) * LS + quad * 8];
#pragma unroll
        for (int mi = 0; mi < 4; ++mi) {
            bf8 af = *(const bf8*)&As[(mi * 16 + l15) * LS + quad * 8];
            acc[mi] = __builtin_amdgcn_mfma_f32_16x16x32_bf16(af, bfr, acc[mi], 0, 0, 0);
        }
    }
    const int n = n0 + wave * 16 + l15;
    if (mode == 0) {
#pragma unroll
        for (int mi = 0; mi < 4; ++mi)
#pragma unroll
            for (int r = 0; r < 4; ++r)
                out[(size_t)(mi * 16 + quad * 4 + r) * ldo + n] = acc[mi][r];
    } else {
#pragma unroll
        for (int mi = 0; mi < 4; ++mi)
            *(f4*)&out[(size_t)n * 64 + mi * 16 + quad * 4] = acc[mi];
    }
}

// ---------------------------------------------------------------------------
// score_gemm v3: single-barrier double-buffered global_load_lds + XOR swizzle.
// Per iter: __syncthreads() drains ONLY the loads issued one iteration ago
// (full latency overlap), then next-tile loads issue and stay in flight
// through the MFMA work. LDS chunk j of row r lives at slot j^((r>>1)&3):
// staging picks source chunk (l&3)^((l>>3)&3), readers slot quad^((l15>>1)&3)
// -> 2 lanes/bank-group on ds_read_b128 (free, m136).
// ---------------------------------------------------------------------------
__global__ __launch_bounds__(256) void score_gemm(
    const __bf16* __restrict__ memb, const __bf16* __restrict__ uaT,
    const float* __restrict__ hWaT, const float* __restrict__ attV,
    float* __restrict__ scoreT) {
    __shared__ __bf16 As[2][128 * 32];
    __shared__ __bf16 Bs[2][128 * 32];
    const int tid = threadIdx.x;
    const int lane = tid & 63, wave = tid >> 6;
    const int wM = wave >> 1, wN = wave & 1;
    const int quad = lane >> 4, l15 = lane & 15;
    const int bidx = blockIdx.x;
    const int mb = (bidx >> 6) * 8 + (bidx & 7);   // same-XCD group shares mb
    const int nb = (bidx >> 3) & 7;
    const int n0 = nb * 128, m0 = mb * 128;

    const int srow = lane >> 2;
    const int scol = ((lane & 3) ^ ((lane >> 3) & 3)) * 8;
    const __bf16* aSrc = memb + (size_t)(m0 + srow) * NHID + scol;
    const __bf16* bSrc = uaT + (size_t)(n0 + srow) * NHID + scol;
    const int rslot = (quad ^ ((l15 >> 1) & 3)) * 8;

    f32x4 acc[4][4] = {};

#pragma unroll
    for (int j = 0; j < 2; ++j) {
        const int c = wave * 2 + j;
        __builtin_amdgcn_global_load_lds(GPTR(aSrc + (size_t)c * 16 * NHID),
                                         LPTR(&As[0][c * 512]), 16, 0, 0);
        __builtin_amdgcn_global_load_lds(GPTR(bSrc + (size_t)c * 16 * NHID),
                                         LPTR(&Bs[0][c * 512]), 16, 0, 0);
    }

    for (int it = 0; it < 32; ++it) {
        const int cur = it & 1, nxt = cur ^ 1;
        __syncthreads();
        if (it + 1 < 32) {
            const int k = (it + 1) * 32;
#pragma unroll
            for (int j = 0; j < 2; ++j) {
                const int c = wave * 2 + j;
                __builtin_amdgcn_global_load_lds(GPTR(aSrc + (size_t)c * 16 * NHID + k),
                                                 LPTR(&As[nxt][c * 512]), 16, 0, 0);
                __builtin_amdgcn_global_load_lds(GPTR(bSrc + (size_t)c * 16 * NHID + k),
                                                 LPTR(&Bs[nxt][c * 512]), 16, 0, 0);
            }
        }
        bf8 af[4], bfr[4];
#pragma unroll
        for (int i = 0; i < 4; ++i)
            af[i] = *(const bf8*)&As[cur][(wM * 64 + i * 16 + l15) * 32 + rslot];
#pragma unroll
        for (int i = 0; i < 4; ++i)
            bfr[i] = *(const bf8*)&Bs[cur][(wN * 64 + i * 16 + l15) * 32 + rslot];
#pragma unroll
        for (int mi = 0; mi < 4; ++mi)
#pragma unroll
            for (int ni = 0; ni < 4; ++ni)
                acc[mi][ni] = __builtin_amdgcn_mfma_f32_16x16x32_bf16(
                    af[mi], bfr[ni], acc[mi][ni], 0, 0, 0);
    }

    const int tglob = mb * 2 + wM;
#pragma unroll
    for (int mi = 0; mi < 4; ++mi) {
        float rs[4] = {0.f, 0.f, 0.f, 0.f};
#pragma unroll
        for (int ni = 0; ni < 4; ++ni) {
            int n = n0 + wN * 64 + ni * 16 + l15;
            f4 hw = *(const f4*)&hWaT[(size_t)n * 64 + mi * 16 + quad * 4];
            float av = attV[n];
#pragma unroll
            for (int r = 0; r < 4; ++r)
                rs[r] += fast_tanh(acc[mi][ni][r] + hw[r]) * av;
        }
#pragma unroll
        for (int r = 0; r < 4; ++r) {
            float v = rs[r];
            v += __shfl_xor(v, 1); v += __shfl_xor(v, 2);
            v += __shfl_xor(v, 4); v += __shfl_xor(v, 8);
            if (l15 == 0) {
                int b = mi * 16 + quad * 4 + r;
                atomicAdd(&scoreT[b * T_LEN + tglob], v);
            }
        }
    }
}

// ---------------------------------------------------------------------------
// fallback score_gemm reading fp32 mem directly (used if ws too small)
// ---------------------------------------------------------------------------
__global__ __launch_bounds__(256) void score_gemm_f32(
    const float* __restrict__ mem, const __bf16* __restrict__ uaT,
    const float* __restrict__ hWaT, const float* __restrict__ attV,
    float* __restrict__ scoreT) {
    __shared__ __bf16 As[128 * LS];
    __shared__ __bf16 Bs[128 * LS];
    const int tid = threadIdx.x;
    const int lane = tid & 63, wave = tid >> 6;
    const int wM = wave >> 1, wN = wave & 1;
    const int quad = lane >> 4, l15 = lane & 15;
    const int mb = blockIdx.x >> 3, nb = blockIdx.x & 7;
    const int n0 = nb * 128;
    const int arow = tid >> 1, ahalf = (tid & 1) * 16;
    const float*  aptr = mem + (size_t)(mb * 128 + arow) * NHID + ahalf;
    const __bf16* bptr = uaT + (size_t)(n0 + arow) * NHID + ahalf;
    f4  ga[4];
    bf8 gb[2];
#pragma unroll
    for (int j = 0; j < 4; ++j) ga[j] = *(const f4*)(aptr + 4 * j);
#pragma unroll
    for (int j = 0; j < 2; ++j) gb[j] = *(const bf8*)(bptr + 8 * j);
    f32x4 acc[4][4] = {};
    for (int k0 = 0; k0 < NHID; k0 += 32) {
        __syncthreads();
#pragma unroll
        for (int j = 0; j < 4; ++j) {
            bf4 w;
            w[0] = (__bf16)ga[j][0]; w[1] = (__bf16)ga[j][1];
            w[2] = (__bf16)ga[j][2]; w[3] = (__bf16)ga[j][3];
            *(bf4*)&As[arow * LS + ahalf + 4 * j] = w;
        }
#pragma unroll
        for (int j = 0; j < 2; ++j) *(bf8*)&Bs[arow * LS + ahalf + 8 * j] = gb[j];
        __syncthreads();
        if (k0 + 32 < NHID) {
#pragma unroll
            for (int j = 0; j < 4; ++j) ga[j] = *(const f4*)(aptr + k0 + 32 + 4 * j);
#pragma unroll
            for (int j = 0; j < 2; ++j) gb[j] = *(const bf8*)(bptr + k0 + 32 + 8 * j);
        }
        bf8 af[4], bfr[4];
#pragma unroll
        for (int i = 0; i < 4; ++i)
            af[i] = *(const bf8*)&As[(wM * 64 + i * 16 + l15) * LS + quad * 8];
#pragma unroll
        for (int i = 0; i < 4; ++i)
            bfr[i] = *(const bf8*)&Bs[(wN * 64 + i * 16 + l15) * LS + quad * 8];
#pragma unroll
        for (int mi = 0; mi < 4; ++mi)
#pragma unroll
            for (int ni = 0; ni < 4; ++ni)
                acc[mi][ni] = __builtin_amdgcn_mfma_f32_16x16x32_bf16(
                    af[mi], bfr[ni], acc[mi][ni], 0, 0, 0);
    }
    const int tglob = mb * 2 + wM;
#pragma unroll
    for (int mi = 0; mi < 4; ++mi) {
        float rs[4] = {0.f, 0.f, 0.f, 0.f};
#pragma unroll
        for (int ni = 0; ni < 4; ++ni) {
            int n = n0 + wN * 64 + ni * 16 + l15;
            f4 hw = *(const f4*)&hWaT[(size_t)n * 64 + mi * 16 + quad * 4];
            float av = attV[n];
#pragma unroll
            for (int r = 0; r < 4; ++r)
                rs[r] += fast_tanh(acc[mi][ni][r] + hw[r]) * av;
        }
#pragma unroll
        for (int r = 0; r < 4; ++r) {
            float v = rs[r];
            v += __shfl_xor(v, 1); v += __shfl_xor(v, 2);
            v += __shfl_xor(v, 4); v += __shfl_xor(v, 8);
            if (l15 == 0) {
                int b = mi * 16 + quad * 4 + r;
                atomicAdd(&scoreT[b * T_LEN + tglob], v);
            }
        }
    }
}

// ---------------------------------------------------------------------------
__global__ void softmax_k(const float* __restrict__ scoreT, float* __restrict__ wts) {
    const int b = blockIdx.x, tid = threadIdx.x;
    const int lane = tid & 63, wave = tid >> 6;
    __shared__ float red[4];
    __shared__ float red2[4];
    float s[4];
    float mx = -1e30f;
#pragma unroll
    for (int i = 0; i < 4; ++i) {
        s[i] = scoreT[b * T_LEN + tid + 256 * i];
        mx = fmaxf(mx, s[i]);
    }
#pragma unroll
    for (int o = 1; o < 64; o <<= 1) mx = fmaxf(mx, __shfl_xor(mx, o));
    if (lane == 0) red[wave] = mx;
    __syncthreads();
    mx = fmaxf(fmaxf(red[0], red[1]), fmaxf(red[2], red[3]));
    float e[4], sum = 0.f;
#pragma unroll
    for (int i = 0; i < 4; ++i) { e[i] = __expf(s[i] - mx); sum += e[i]; }
#pragma unroll
    for (int o = 1; o < 64; o <<= 1) sum += __shfl_xor(sum, o);
    if (lane == 0) red2[wave] = sum;
    __syncthreads();
    sum = red2[0] + red2[1] + red2[2] + red2[3];
    float inv = 1.0f / sum;
#pragma unroll
    for (int i = 0; i < 4; ++i) wts[b * T_LEN + tid + 256 * i] = e[i] * inv;
}

// ---------------------------------------------------------------------------
// context from bf16 pool (L3-resident, half the traffic)
// ---------------------------------------------------------------------------
__global__ void context_kb(const float* __restrict__ wts, const __bf16* __restrict__ memb,
                           float* __restrict__ ctx) {
    const int b = blockIdx.x >> 3, tc = blockIdx.x & 7;
    const int n4 = threadIdx.x * 4;
    f4 acc = {0.f, 0.f, 0.f, 0.f};
    const int t0 = tc * 128;
    for (int t = t0; t < t0 + 128; ++t) {
        float w = wts[b * T_LEN + t];
        bf4 m = *(const bf4*)(memb + ((size_t)t * BATCH + b) * NHID + n4);
#pragma unroll
        for (int i = 0; i < 4; ++i) acc[i] += w * (float)m[i];
    }
#pragma unroll
    for (int i = 0; i < 4; ++i) atomicAdd(&ctx[(size_t)b * NHID + n4 + i], acc[i]);
}

__global__ void context_k(const float* __restrict__ wts, const float* __restrict__ mem,
                          float* __restrict__ ctx) {
    const int b = blockIdx.x >> 3, tc = blockIdx.x & 7;
    const int n4 = threadIdx.x * 4;
    f4 acc = {0.f, 0.f, 0.f, 0.f};
    const int t0 = tc * 128;
    for (int t = t0; t < t0 + 128; ++t) {
        float w = wts[b * T_LEN + t];
        f4 m = *(const f4*)(mem + ((size_t)t * BATCH + b) * NHID + n4);
        acc += w * m;
    }
#pragma unroll
    for (int i = 0; i < 4; ++i) atomicAdd(&ctx[(size_t)b * NHID + n4 + i], acc[i]);
}

__global__ void ctx_cvt(const float* __restrict__ ctx, __bf16* __restrict__ Ag) {
    const int b = blockIdx.x, tid = threadIdx.x;
#pragma unroll
    for (int i = 0; i < 4; ++i) {
        int n = tid + 256 * i;
        Ag[(size_t)b * KCAT + H2 + n] = (__bf16)ctx[(size_t)b * NHID + n];
    }
}

// ---------------------------------------------------------------------------
__global__ void lstm_k(const float* __restrict__ gates, const float* __restrict__ bl,
                       const float* __restrict__ cprev, float* __restrict__ out_ct,
                       float* __restrict__ out_ht, __bf16* __restrict__ htb) {
    const int idx = blockIdx.x * 256 + threadIdx.x;
    const int b = idx >> 11, k = idx & 2047;
    float gi = gates[(size_t)b * G4 + k]          + bl[k];
    float gf = gates[(size_t)b * G4 + H2 + k]     + bl[H2 + k];
    float gg = gates[(size_t)b * G4 + 2 * H2 + k] + bl[2 * H2 + k];
    float go = gates[(size_t)b * G4 + 3 * H2 + k] + bl[3 * H2 + k];
    float ct = fast_sig(gf) * cprev[idx] + fast_sig(gi) * fast_tanh(gg);
    float ht = fast_sig(go) * fast_tanh(ct);
    out_ct[idx] = ct;
    if (k < NHID) {
        out_ht[(size_t)b * NHID + k] = ht;
        htb[(size_t)b * NHID + k]    = (__bf16)ht;
    }
}

// ---------------------------------------------------------------------------
// dec_gemm with register-prefetch pipeline
// ---------------------------------------------------------------------------
__global__ __launch_bounds__(256) void dec_gemm(
    const __bf16* __restrict__ htb, const float* __restrict__ dw,
    const float* __restrict__ db, float* __restrict__ outd) {
    __shared__ __bf16 As[64 * LS];
    __shared__ __bf16 Bs[128 * LS];
    const int tid = threadIdx.x;
    const int lane = tid & 63, wave = tid >> 6;
    const int quad = lane >> 4, l15 = lane & 15;
    const int n0 = blockIdx.x * 128;
    const int ar = tid >> 2, ac = (tid & 3) * 8;
    const int br = tid >> 1, bc = (tid & 1) * 16;
    const int vrow = n0 + br;
    const bool vok = vrow < NVOC;

    f32x4 acc[4][2] = {};
    bf8 pa = *(const bf8*)(htb + (size_t)ar * NHID + ac);
    f4 pv[4] = {};
#pragma unroll
    for (int j = 0; j < 4; ++j)
        if (vok) pv[j] = *(const f4*)(dw + (size_t)vrow * NHID + bc + 4 * j);

    for (int k0 = 0; k0 < NHID; k0 += 32) {
        __syncthreads();
        *(bf8*)&As[ar * LS + ac] = pa;
#pragma unroll
        for (int j = 0; j < 4; ++j) {
            bf4 w;
            w[0] = (__bf16)pv[j][0]; w[1] = (__bf16)pv[j][1];
            w[2] = (__bf16)pv[j][2]; w[3] = (__bf16)pv[j][3];
            *(bf4*)&Bs[br * LS + bc + 4 * j] = w;
        }
        __syncthreads();
        if (k0 + 32 < NHID) {
            pa = *(const bf8*)(htb + (size_t)ar * NHID + k0 + 32 + ac);
#pragma unroll
            for (int j = 0; j < 4; ++j)
                if (vok) pv[j] = *(const f4*)(dw + (size_t)vrow * NHID + k0 + 32 + bc + 4 * j);
        }
#pragma unroll
        for (int ni = 0; ni < 2; ++ni) {
            bf8 bfr = *(const bf8*)&Bs[(wave * 32 + ni * 16 + l15) * LS + quad * 8];
#pragma unroll
            for (int mi = 0; mi < 4; ++mi) {
                bf8 af = *(const bf8*)&As[(mi * 16 + l15) * LS + quad * 8];
                acc[mi][ni] = __builtin_amdgcn_mfma_f32_16x16x32_bf16(af, bfr, acc[mi][ni], 0, 0, 0);
            }
        }
    }
#pragma unroll
    for (int ni = 0; ni < 2; ++ni) {
        int n = n0 + wave * 32 + ni * 16 + l15;
        if (n < NVOC) {
            float bb = db[n];
#pragma unroll
            for (int mi = 0; mi < 4; ++mi)
#pragma unroll
                for (int r = 0; r < 4; ++r)
                    outd[(size_t)(mi * 16 + quad * 4 + r) * NVOC + n] = acc[mi][ni][r] + bb;
        }
    }
}

// ---------------------------------------------------------------------------
extern "C" void kernel_launch(void* const* d_in, const int* in_sizes, int n_in,
                              void* d_out, int out_size, void* d_ws, size_t ws_size,
                              hipStream_t stream) {
    (void)in_sizes; (void)n_in; (void)out_size;
    const int*   inp   = (const int*)d_in[0];
    const float* mem   = (const float*)d_in[1];
    const float* hprev = (const float*)d_in[2];
    const float* cprev = (const float*)d_in[3];
    const float* encw  = (const float*)d_in[4];
    const float* attWa = (const float*)d_in[5];
    const float* attUa = (const float*)d_in[6];
    const float* attV  = (const float*)d_in[7];
    const float* Wih   = (const float*)d_in[8];
    const float* Whh   = (const float*)d_in[9];
    const float* blstm = (const float*)d_in[10];
    const float* decw  = (const float*)d_in[11];
    const float* decb  = (const float*)d_in[12];

    char* ws = (char*)d_ws;
    float*  scoreT = (float*)(ws);              // 256 KB  [b][t]
    float*  wts    = (float*)(ws + 262144);     // 256 KB  [b][t]
    float*  hWaT   = (float*)(ws + 524288);     // 256 KB  [n][b]
    float*  ctx    = (float*)(ws + 786432);     // 256 KB  [b][n]
    float*  gates  = (float*)(ws + 1048576);    // 2 MB    [b][8192]
    __bf16* Ag     = (__bf16*)(ws + 3145728);   // 384 KB  [b][3072]
    __bf16* htb    = (__bf16*)(ws + 3538944);   // 128 KB  [b][1024]
    __bf16* uaT    = (__bf16*)(ws + 3670016);   // 2 MB    [n][k]
    __bf16* memb   = (__bf16*)(ws + 5767168);   // 134.2 MB [t*64+b][k]
    const size_t ws_need = 5767168 + (size_t)T_LEN * BATCH * NHID * 2;

    float* outdec = (float*)d_out;
    float* outht  = outdec + (size_t)BATCH * NVOC;
    float* outct  = outht + BATCH * NHID;

    hipMemsetAsync(scoreT, 0, 262144, stream);
    hipMemsetAsync(ctx, 0, 262144, stream);
    hipLaunchKernelGGL(transpose_ua, dim3(256), dim3(256), 0, stream, attUa, uaT);
    hipLaunchKernelGGL(prep_emb_h, dim3(64), dim3(256), 0, stream, inp, encw, hprev, Ag);
    hipLaunchKernelGGL(small_gemm, dim3(16), dim3(256), 0, stream,
                       Ag + NHID, KCAT, NHID, NHID, attWa, attWa, NHID, hWaT, 64, 1);
    const bool big_ws = ws_size >= ws_need;
    if (big_ws) {
        hipLaunchKernelGGL(cvt_mem, dim3(32768), dim3(256), 0, stream, mem, memb);
        hipLaunchKernelGGL(score_gemm, dim3(4096), dim3(256), 0, stream,
                           memb, uaT, hWaT, attV, scoreT);
    } else {
        hipLaunchKernelGGL(score_gemm_f32, dim3(4096), dim3(256), 0, stream,
                           mem, uaT, hWaT, attV, scoreT);
    }
    hipLaunchKernelGGL(softmax_k, dim3(64), dim3(256), 0, stream, scoreT, wts);
    if (big_ws) {
        hipLaunchKernelGGL(context_kb, dim3(512), dim3(256), 0, stream, wts, memb, ctx);
    } else {
        hipLaunchKernelGGL(context_k, dim3(512), dim3(256), 0, stream, wts, mem, ctx);
    }
    hipLaunchKernelGGL(ctx_cvt, dim3(64), dim3(256), 0, stream, ctx, Ag);
    hipLaunchKernelGGL(small_gemm, dim3(128), dim3(256), 0, stream,
                       Ag, KCAT, KCAT, NHID, Wih, Whh, G4, gates, G4, 0);
    hipLaunchKernelGGL(lstm_k, dim3(512), dim3(256), 0, stream,
                       gates, blstm, cprev, outct, outht, htb);
    hipLaunchKernelGGL(dec_gemm, dim3((NVOC + 127) / 128), dim3(256), 0, stream,
                       htb, decw, decb, outdec);
}